// Round 1
// baseline (327.035 us; speedup 1.0000x reference)
//
#include <hip/hip_runtime.h>

static constexpr int T_LEN = 512;

__device__ __forceinline__ float fsigm(float x) {
    // 1 / (1 + e^-x)
    return __builtin_amdgcn_rcpf(1.0f + __expf(-x));
}
__device__ __forceinline__ float ftanh(float x) {
    // tanh(x) = 1 - 2/(1 + e^{2x})
    return 1.0f - 2.0f * __builtin_amdgcn_rcpf(1.0f + __expf(2.0f * x));
}

// One wave = 2 batch elements (32 lanes each).
// Lane (j = lam&15, s = lam>>4): owns gate-unit j, k-half s of all dot products.
// Weights in VGPRs, h-state halves replicated, combines via shfl_xor(16),
// h broadcast via 8 shfl per layer per step. No LDS, no barriers.
__global__ __launch_bounds__(256, 1) void gru2_fused(
    const float* __restrict__ x,
    const float* __restrict__ Wih0, const float* __restrict__ Whh0,
    const float* __restrict__ bih0, const float* __restrict__ bhh0,
    const float* __restrict__ Wih1, const float* __restrict__ Whh1,
    const float* __restrict__ bih1, const float* __restrict__ bhh1,
    const float* __restrict__ fcw,  const float* __restrict__ fcb,
    float* __restrict__ out)
{
    const int tid   = threadIdx.x;
    const int lane  = tid & 63;
    const int b     = blockIdx.x * 8 + (tid >> 5);
    const int lam   = tid & 31;
    const int j     = lam & 15;   // gate unit
    const int s     = lam >> 4;   // k-half
    const int sbase = (lane & 32) + 8 * s;  // shfl source base for h-broadcast

    // ---- per-lane weight registers ----
    float wih0[3][16], whh0[3][8], wih1[3][8], whh1[3][8];
    float bi0[3], bh0[3], bi1[3], bh1[3];
#pragma unroll
    for (int g = 0; g < 3; ++g) {
        const int row = g * 16 + j;
        {
            const float* p = Wih0 + row * 32 + 16 * s;
#pragma unroll
            for (int q = 0; q < 4; ++q) {
                float4 v = *(const float4*)(p + 4 * q);
                wih0[g][4*q+0] = v.x; wih0[g][4*q+1] = v.y;
                wih0[g][4*q+2] = v.z; wih0[g][4*q+3] = v.w;
            }
        }
        {
            const float* p = Whh0 + row * 16 + 8 * s;
#pragma unroll
            for (int q = 0; q < 2; ++q) {
                float4 v = *(const float4*)(p + 4 * q);
                whh0[g][4*q+0] = v.x; whh0[g][4*q+1] = v.y;
                whh0[g][4*q+2] = v.z; whh0[g][4*q+3] = v.w;
            }
        }
        {
            const float* p = Wih1 + row * 16 + 8 * s;
#pragma unroll
            for (int q = 0; q < 2; ++q) {
                float4 v = *(const float4*)(p + 4 * q);
                wih1[g][4*q+0] = v.x; wih1[g][4*q+1] = v.y;
                wih1[g][4*q+2] = v.z; wih1[g][4*q+3] = v.w;
            }
        }
        {
            const float* p = Whh1 + row * 16 + 8 * s;
#pragma unroll
            for (int q = 0; q < 2; ++q) {
                float4 v = *(const float4*)(p + 4 * q);
                whh1[g][4*q+0] = v.x; whh1[g][4*q+1] = v.y;
                whh1[g][4*q+2] = v.z; whh1[g][4*q+3] = v.w;
            }
        }
        bi0[g] = bih0[row]; bh0[g] = bhh0[row];
        bi1[g] = bih1[row]; bh1[g] = bhh1[row];
    }

    // ---- state ----
    float h0h[8], h1h[8];
#pragma unroll
    for (int k = 0; k < 8; ++k) { h0h[k] = 0.f; h1h[k] = 0.f; }
    float h0self = 0.f, h1self = 0.f;

    const float* xb = x + ((size_t)b * T_LEN) * 32 + 16 * s;

    // 2-deep x prefetch ring (hides HBM latency across one full step)
    float4 bufA[4], bufB[4];
#pragma unroll
    for (int q = 0; q < 4; ++q) {
        bufA[q] = *(const float4*)(xb + 0 * 32 + 4 * q);
        bufB[q] = *(const float4*)(xb + 1 * 32 + 4 * q);
    }

    auto step = [&](float4 (&buf)[4], int tnext) {
        // layer-0 input-gate partials from x (K-half of 32)
        float xa0 = 0.f, xa1 = 0.f, xa2 = 0.f;
#pragma unroll
        for (int q = 0; q < 4; ++q) {
            float4 v = buf[q];
            xa0 = fmaf(wih0[0][4*q+0], v.x, xa0);
            xa0 = fmaf(wih0[0][4*q+1], v.y, xa0);
            xa0 = fmaf(wih0[0][4*q+2], v.z, xa0);
            xa0 = fmaf(wih0[0][4*q+3], v.w, xa0);
            xa1 = fmaf(wih0[1][4*q+0], v.x, xa1);
            xa1 = fmaf(wih0[1][4*q+1], v.y, xa1);
            xa1 = fmaf(wih0[1][4*q+2], v.z, xa1);
            xa1 = fmaf(wih0[1][4*q+3], v.w, xa1);
            xa2 = fmaf(wih0[2][4*q+0], v.x, xa2);
            xa2 = fmaf(wih0[2][4*q+1], v.y, xa2);
            xa2 = fmaf(wih0[2][4*q+2], v.z, xa2);
            xa2 = fmaf(wih0[2][4*q+3], v.w, xa2);
        }
        // issue prefetch for t+2 (consumed two steps later)
#pragma unroll
        for (int q = 0; q < 4; ++q)
            buf[q] = *(const float4*)(xb + tnext * 32 + 4 * q);

        // recurrent partials: layer0 (h0) and layer1 (h1, pre-update state)
        float ha0 = 0.f, ha1 = 0.f, ha2 = 0.f;
        float hc0 = 0.f, hc1 = 0.f, hc2 = 0.f;
#pragma unroll
        for (int k = 0; k < 8; ++k) {
            ha0 = fmaf(whh0[0][k], h0h[k], ha0);
            ha1 = fmaf(whh0[1][k], h0h[k], ha1);
            ha2 = fmaf(whh0[2][k], h0h[k], ha2);
            hc0 = fmaf(whh1[0][k], h1h[k], hc0);
            hc1 = fmaf(whh1[1][k], h1h[k], hc1);
            hc2 = fmaf(whh1[2][k], h1h[k], hc2);
        }

        // combine halves (both halves end up with full sums; fp-add commutative)
        float xr = xa0 + __shfl_xor(xa0, 16, 64) + bi0[0];
        float xz = xa1 + __shfl_xor(xa1, 16, 64) + bi0[1];
        float xn = xa2 + __shfl_xor(xa2, 16, 64) + bi0[2];
        float hr = ha0 + __shfl_xor(ha0, 16, 64) + bh0[0];
        float hz = ha1 + __shfl_xor(ha1, 16, 64) + bh0[1];
        float hn = ha2 + __shfl_xor(ha2, 16, 64) + bh0[2];
        float g1r = hc0 + __shfl_xor(hc0, 16, 64) + bh1[0];
        float g1z = hc1 + __shfl_xor(hc1, 16, 64) + bh1[1];
        float g1n = hc2 + __shfl_xor(hc2, 16, 64) + bh1[2];

        // layer-0 gates + update (unit j)
        float r = fsigm(xr + hr);
        float z = fsigm(xz + hz);
        float n = ftanh(xn + r * hn);
        h0self = (1.f - z) * n + z * h0self;

        // broadcast new h0 half to all lanes
#pragma unroll
        for (int k = 0; k < 8; ++k)
            h0h[k] = __shfl(h0self, sbase + k, 64);

        // layer-1 input gates from new h0
        float ya0 = 0.f, ya1 = 0.f, ya2 = 0.f;
#pragma unroll
        for (int k = 0; k < 8; ++k) {
            ya0 = fmaf(wih1[0][k], h0h[k], ya0);
            ya1 = fmaf(wih1[1][k], h0h[k], ya1);
            ya2 = fmaf(wih1[2][k], h0h[k], ya2);
        }
        float yr = ya0 + __shfl_xor(ya0, 16, 64) + bi1[0];
        float yz = ya1 + __shfl_xor(ya1, 16, 64) + bi1[1];
        float yn = ya2 + __shfl_xor(ya2, 16, 64) + bi1[2];

        // layer-1 gates + update
        float r1 = fsigm(yr + g1r);
        float z1 = fsigm(yz + g1z);
        float n1 = ftanh(yn + r1 * g1n);
        h1self = (1.f - z1) * n1 + z1 * h1self;

        // broadcast new h1 half
#pragma unroll
        for (int k = 0; k < 8; ++k)
            h1h[k] = __shfl(h1self, sbase + k, 64);
    };

    for (int t = 0; t < T_LEN; t += 2) {
        int tn0 = (t + 2 < T_LEN) ? (t + 2) : (T_LEN - 1);
        int tn1 = (t + 3 < T_LEN) ? (t + 3) : (T_LEN - 1);
        step(bufA, tn0);
        step(bufB, tn1);
    }

    // ---- final FC: out[b] = fc_w . h1_final + fc_b ----
    float part = 0.f;
#pragma unroll
    for (int k = 0; k < 8; ++k)
        part = fmaf(fcw[8 * s + k], h1h[k], part);
    part += __shfl_xor(part, 16, 64);
    if (lam == 0) out[b] = part + fcb[0];
}

extern "C" void kernel_launch(void* const* d_in, const int* in_sizes, int n_in,
                              void* d_out, int out_size, void* d_ws, size_t ws_size,
                              hipStream_t stream) {
    const float* x    = (const float*)d_in[0];
    const float* Wih0 = (const float*)d_in[1];
    const float* Whh0 = (const float*)d_in[2];
    const float* bih0 = (const float*)d_in[3];
    const float* bhh0 = (const float*)d_in[4];
    const float* Wih1 = (const float*)d_in[5];
    const float* Whh1 = (const float*)d_in[6];
    const float* bih1 = (const float*)d_in[7];
    const float* bhh1 = (const float*)d_in[8];
    const float* fcw  = (const float*)d_in[9];
    const float* fcb  = (const float*)d_in[10];

    // 2048 batch elems, 8 per block (32 lanes each) -> 256 blocks x 256 threads
    gru2_fused<<<256, 256, 0, stream>>>(x, Wih0, Whh0, bih0, bhh0,
                                        Wih1, Whh1, bih1, bhh1, fcw, fcb,
                                        (float*)d_out);
}